// Round 11
// baseline (528.603 us; speedup 1.0000x reference)
//
#include <hip/hip_runtime.h>
#include <hip/hip_bf16.h>

// GCN (2-layer, PyG-style symmetric norm + self loops) + edge MLP.
//  - CSR by dst (hist -> 3-level scan -> fill). No fp32 atomics.
//  - gcn_conv: t' = (h@W)*dinv[row], stored FEATURE-SLICED [4][N][16];
//    aggregation runs per 16-feature slice so the gather table is 3.2MB =
//    per-XCD-L2-resident.  out[v] = relu(dinv[v]*(t'[v]+sum t'[s]) + b).
//  - Edge MLP: ef@Wm1 = A[src]+B[dst], A/B precomputed per node.
// R2: 3-level scan (was 111us @ 0.14% occ).  R3: edge_mlp in CSR order.
// R4: epilogue fusion.  R5/R6: readlane batch, dinv folded into rows.
// R7: REGRESSED (TLP starve).  R8/R9: deeper pipes plateaued ~70-75us ->
//     gather is L2/L3-service-bound on a 12.8MB random-gather table.
// R10: FEATURE-SLICED aggregation: 4 slices x 3.2MB (L2-resident);
//     16 lanes/edge, 4 edges per load instr; slice-major producer writes;
//     epilogue GEMMs un-fused again (gemm2, gemm3).
//     (resubmitted: R10 bench never acquired a GPU)

#define HDIM 64
#define CDIM 16
#define FS   16      // slice width
#define NSL  4       // slices

static inline int ceil_div(int a, int b){ return (a+b-1)/b; }

__global__ void k_zero_i32(int* p, int n){
  int i = blockIdx.x*blockDim.x + threadIdx.x;
  if(i<n) p[i]=0;
}

__global__ void k_hist(const int* __restrict__ dst, int* __restrict__ cnt, int E){
  int e = blockIdx.x*blockDim.x + threadIdx.x;
  if(e<E) atomicAdd(&cnt[dst[e]], 1);
}

__global__ __launch_bounds__(256) void k_blocksum(const int* __restrict__ cnt,
                                                  int* __restrict__ bsum, int N){
  __shared__ int part[4];
  int i = blockIdx.x*256 + threadIdx.x;
  int v = (i<N) ? cnt[i] : 0;
  #pragma unroll
  for(int off=32; off>0; off>>=1) v += __shfl_down(v, off, 64);
  if((threadIdx.x & 63)==0) part[threadIdx.x>>6] = v;
  __syncthreads();
  if(threadIdx.x==0) bsum[blockIdx.x] = part[0]+part[1]+part[2]+part[3];
}

__global__ __launch_bounds__(1024) void k_scan_bsums(int* __restrict__ bsum, int nb){
  __shared__ int tmp[1024];
  int tid = threadIdx.x;
  int v = (tid<nb) ? bsum[tid] : 0;
  tmp[tid] = v; __syncthreads();
  for(int off=1; off<1024; off<<=1){
    int add = (tid>=off) ? tmp[tid-off] : 0;
    __syncthreads();
    tmp[tid] += add;
    __syncthreads();
  }
  if(tid<nb) bsum[tid] = tmp[tid] - v;   // exclusive
}

__global__ __launch_bounds__(256) void k_write_prefix(const int* __restrict__ cnt,
                                                      const int* __restrict__ bsum,
                                                      int* __restrict__ row_start,
                                                      int* __restrict__ cursor,
                                                      float* __restrict__ dinv, int N){
  __shared__ int tmp[256];
  int tid = threadIdx.x;
  int i = blockIdx.x*256 + tid;
  int v = (i<N) ? cnt[i] : 0;
  tmp[tid] = v; __syncthreads();
  for(int off=1; off<256; off<<=1){
    int add = (tid>=off) ? tmp[tid-off] : 0;
    __syncthreads();
    tmp[tid] += add;
    __syncthreads();
  }
  if(i<N){
    int ex = bsum[blockIdx.x] + tmp[tid] - v;
    row_start[i] = ex;
    cursor[i]    = ex;
    dinv[i]      = 1.0f / sqrtf(1.0f + (float)v);  // deg >= 1 via self-loop
  }
}

__global__ void k_fill(const int* __restrict__ src, const int* __restrict__ dst,
                       int* __restrict__ cursor,
                       int* __restrict__ csr_src, int* __restrict__ csr_dst,
                       int* __restrict__ csr_eid, int E){
  int e = blockIdx.x*blockDim.x + threadIdx.x;
  if(e>=E) return;
  int s = src[e], d = dst[e];
  int pos = atomicAdd(&cursor[d], 1);
  csr_src[pos] = s;
  csr_dst[pos] = d;
  csr_eid[pos] = e;
}

// t_sliced[c/16][n][c%16] = (sum_k in[n][k]*W[k][c]) * dscale[n].
// One block = 4 nodes; input rows in LDS; W coalesced, cache-resident.
template<int K>
__global__ __launch_bounds__(256) void k_gemm_sliced(const float* __restrict__ in,
                                                     const float* __restrict__ W,
                                                     const float* __restrict__ dscale,
                                                     float* __restrict__ tsl, int N){
  __shared__ float srow[4*K];
  int n0 = blockIdx.x*4;
  for(int i=threadIdx.x; i<4*K; i+=256){
    int g = n0*K + i;
    srow[i] = (g < N*K) ? in[g] : 0.f;
  }
  __syncthreads();
  int c = threadIdx.x & 63;
  int y = threadIdx.x >> 6;
  int n = n0+y;
  if(n>=N) return;
  float acc=0.f;
  #pragma unroll
  for(int k=0;k<K;k++) acc += srow[y*K+k]*W[k*HDIM+c];
  size_t ss = (size_t)N*FS;               // slice stride
  tsl[(size_t)(c>>4)*ss + (size_t)n*FS + (c&15)] = acc*dscale[n];
}

// Per-slice gather-aggregate: one wave per node per slice; 16 lanes/edge,
// 4 edges per load instruction. Table slice = 3.2MB -> per-XCD L2 resident.
// grid.x = NSL*nbs; blocks dispatch in x order so one slice is hot at a time.
__global__ __launch_bounds__(256) void k_agg_slice(const float* __restrict__ tsl,
                                                   const int* __restrict__ csr_src,
                                                   const int* __restrict__ row_start,
                                                   const int* __restrict__ cnt,
                                                   const float* __restrict__ dinv,
                                                   const float* __restrict__ bias,
                                                   float* __restrict__ h,   // [N][64]
                                                   int N, int nbs){
  unsigned bx = blockIdx.x;
  int slice = bx / (unsigned)nbs;
  int blk   = bx % (unsigned)nbs;
  int lane  = threadIdx.x & 63;
  int w     = threadIdx.x >> 6;
  int v     = blk*4 + w;
  if(v >= N) return;                       // whole wave exits together
  int feat = lane & 15;
  int grp  = lane >> 4;
  const float* __restrict__ t = tsl + (size_t)slice * ((size_t)N*FS);

  float dv  = dinv[v];
  int   j0  = row_start[v];
  int   deg = cnt[v];

  float a0 = (grp==0) ? t[(size_t)v*FS + feat] : 0.f;   // self term
  float a1 = 0.f, a2 = 0.f, a3 = 0.f;

  int k = 0;
  for(; k+16<=deg; k+=16){                 // 16 edges per iter, no masking
    int b = j0 + k + grp;
    int s0 = csr_src[b];                   // 16-lane broadcast loads
    int s1 = csr_src[b+4];
    int s2 = csr_src[b+8];
    int s3 = csr_src[b+12];
    float t0 = t[(size_t)s0*FS+feat];      // 64B row gathers, L2-hit
    float t1 = t[(size_t)s1*FS+feat];
    float t2 = t[(size_t)s2*FS+feat];
    float t3 = t[(size_t)s3*FS+feat];
    a0+=t0; a1+=t1; a2+=t2; a3+=t3;
  }
  for(; k<deg; k+=4){                      // masked tail, 4 edges per iter
    int e = k + grp;
    int s = csr_src[j0 + (e<deg ? e : deg-1)];
    float val = (e<deg) ? t[(size_t)s*FS+feat] : 0.f;
    a0 += val;
  }
  float a = (a0+a1)+(a2+a3);
  a += __shfl_xor(a, 16, 64);              // reduce the 4 edge-groups
  a += __shfl_xor(a, 32, 64);
  float r = a*dv + bias[slice*FS + feat];
  r = r>0.f ? r : 0.f;
  if(grp==0) h[(size_t)v*HDIM + slice*FS + feat] = r;
}

// AB[n][0..63] = h2[n] @ Wm1[0:64,:]; AB[n][64..127] = h2[n] @ Wm1[64:128,:]
__global__ __launch_bounds__(256) void k_gemm3(const float* __restrict__ h2,
                                               const float* __restrict__ Wm1,
                                               float* __restrict__ AB, int N){
  __shared__ float srow[2*HDIM];
  int n0 = blockIdx.x*2;
  for(int i=threadIdx.x; i<2*HDIM; i+=256){
    int g = n0*HDIM + i;
    srow[i] = (g < N*HDIM) ? h2[g] : 0.f;
  }
  __syncthreads();
  int c = threadIdx.x & 127;
  int y = threadIdx.x >> 7;
  int n = n0+y;
  if(n>=N) return;
  const float* Wcol = (c < HDIM) ? (Wm1 + c) : (Wm1 + HDIM*HDIM + (c-HDIM));
  float acc=0.f;
  #pragma unroll
  for(int k=0;k<HDIM;k++) acc += srow[y*HDIM+k]*Wcol[k*HDIM];
  AB[(size_t)n*128+c]=acc;
}

// Edge MLP in CSR(dst) order: thread j -> (s, d, eid). Consecutive threads share
// d -> B[d] reads broadcast/stream. A[s] random: 16 float4 loads in flight.
__global__ __launch_bounds__(256) void k_edge_mlp(const int* __restrict__ csr_src,
                                                  const int* __restrict__ csr_dst,
                                                  const int* __restrict__ csr_eid,
                                                  const float* __restrict__ AB,
                                                  const float* __restrict__ bm1,
                                                  const float* __restrict__ Wm2,
                                                  const float* __restrict__ bm2,
                                                  float* __restrict__ out, int E){
  int j = blockIdx.x*blockDim.x + threadIdx.x;
  if(j>=E) return;
  int s = csr_src[j], d = csr_dst[j], eid = csr_eid[j];
  const float4* Af = (const float4*)(AB + (size_t)s*128);
  const float4* Bf = (const float4*)(AB + (size_t)d*128 + 64);
  const float4* bm1f = (const float4*)bm1;
  const float4* bm2f = (const float4*)bm2;

  float4 a[16];
  #pragma unroll
  for(int k0=0;k0<16;k0++) a[k0] = Af[k0];   // random-side gather, 16 in flight

  float acc[CDIM];
  {
    float4 c0 = bm2f[0], c1 = bm2f[1], c2 = bm2f[2], c3 = bm2f[3];
    acc[0]=c0.x; acc[1]=c0.y; acc[2]=c0.z; acc[3]=c0.w;
    acc[4]=c1.x; acc[5]=c1.y; acc[6]=c1.z; acc[7]=c1.w;
    acc[8]=c2.x; acc[9]=c2.y; acc[10]=c2.z; acc[11]=c2.w;
    acc[12]=c3.x; acc[13]=c3.y; acc[14]=c3.z; acc[15]=c3.w;
  }
  #pragma unroll
  for(int k0=0;k0<16;k0++){
    float4 b  = Bf[k0];     // same d across wave -> broadcast / L1-hit
    float4 bb = bm1f[k0];   // wave-uniform -> s_load
    float z0 = a[k0].x+b.x+bb.x; z0 = z0>0.f? z0:0.f;
    float z1 = a[k0].y+b.y+bb.y; z1 = z1>0.f? z1:0.f;
    float z2 = a[k0].z+b.z+bb.z; z2 = z2>0.f? z2:0.f;
    float z3 = a[k0].w+b.w+bb.w; z3 = z3>0.f? z3:0.f;
    #pragma unroll
    for(int c=0;c<CDIM;c++){
      acc[c] += z0 * Wm2[(k0*4+0)*CDIM + c];
      acc[c] += z1 * Wm2[(k0*4+1)*CDIM + c];
      acc[c] += z2 * Wm2[(k0*4+2)*CDIM + c];
      acc[c] += z3 * Wm2[(k0*4+3)*CDIM + c];
    }
  }
  float4* o = (float4*)(out + (size_t)eid*CDIM);
  o[0] = make_float4(acc[0],acc[1],acc[2],acc[3]);
  o[1] = make_float4(acc[4],acc[5],acc[6],acc[7]);
  o[2] = make_float4(acc[8],acc[9],acc[10],acc[11]);
  o[3] = make_float4(acc[12],acc[13],acc[14],acc[15]);
}

extern "C" void kernel_launch(void* const* d_in, const int* in_sizes, int n_in,
                              void* d_out, int out_size, void* d_ws, size_t ws_size,
                              hipStream_t stream) {
  const float* x   = (const float*)d_in[0];
  const int*   ei  = (const int*)  d_in[1];
  const float* W1  = (const float*)d_in[2];
  const float* b1  = (const float*)d_in[3];
  const float* W2  = (const float*)d_in[4];
  const float* b2  = (const float*)d_in[5];
  const float* Wm1 = (const float*)d_in[6];
  const float* bm1 = (const float*)d_in[7];
  const float* Wm2 = (const float*)d_in[8];
  const float* bm2 = (const float*)d_in[9];
  float* out = (float*)d_out;

  const int N = in_sizes[0]/128;
  const int E = in_sizes[1]/2;
  const int* src = ei;
  const int* dst = ei + E;

  const int NB  = ceil_div(N,256);
  const int nbs = ceil_div(N,4);     // node-blocks per slice

  // ws layout (256B-aligned). Aliasing:
  //   R (25.6MB) = t1_sliced (low 12.8) + t2_sliced (high 12.8); AB = all of R
  //   (t1,t2 dead before gemm3 writes AB).  h (12.8MB) serves h1 then h2.
  char* ws = (char*)d_ws;
  size_t off = 0;
  auto alloc = [&](size_t bytes)->char*{
    char* p = ws + off; off += (bytes + 255) & ~(size_t)255; return p;
  };
  int*   cnt       = (int*)  alloc((size_t)N*4);
  int*   row_start = (int*)  alloc((size_t)N*4);
  int*   cursor    = (int*)  alloc((size_t)N*4);
  float* dinv      = (float*)alloc((size_t)N*4);
  int*   bsum      = (int*)  alloc((size_t)NB*4);
  int*   csr_src   = (int*)  alloc((size_t)E*4);
  int*   csr_dst   = (int*)  alloc((size_t)E*4);
  int*   csr_eid   = (int*)  alloc((size_t)E*4);
  float* AB        = (float*)alloc((size_t)N*128*4);   // 25.6MB region R
  float* t1s       = AB;                               // [4][N][16]
  float* t2s       = AB + (size_t)N*64;                // [4][N][16]
  float* h         = (float*)alloc((size_t)N*64*4);    // h1 then h2

  // --- CSR build ---
  k_zero_i32    <<<ceil_div(N,256),256,0,stream>>>(cnt, N);
  k_hist        <<<ceil_div(E,256),256,0,stream>>>(dst, cnt, E);
  k_blocksum    <<<NB,256,0,stream>>>(cnt, bsum, N);
  k_scan_bsums  <<<1,1024,0,stream>>>(bsum, NB);
  k_write_prefix<<<NB,256,0,stream>>>(cnt, bsum, row_start, cursor, dinv, N);
  k_fill        <<<ceil_div(E,256),256,0,stream>>>(src, dst, cursor,
                                                   csr_src, csr_dst, csr_eid, E);

  // --- layer 1: t1' = (x@W1)*dinv, sliced ---
  k_gemm_sliced<128><<<ceil_div(N,4),256,0,stream>>>(x, W1, dinv, t1s, N);
  // --- agg1 (4 slices, one launch): h1 = relu(...) ---
  k_agg_slice<<<NSL*nbs,256,0,stream>>>(t1s, csr_src, row_start, cnt,
                                        dinv, b1, h, N, nbs);
  // --- layer 2: t2' = (h1@W2)*dinv, sliced ---
  k_gemm_sliced<64><<<ceil_div(N,4),256,0,stream>>>(h, W2, dinv, t2s, N);
  // --- agg2: h2 = relu(...) (reuses h buffer) ---
  k_agg_slice<<<NSL*nbs,256,0,stream>>>(t2s, csr_src, row_start, cnt,
                                        dinv, b2, h, N, nbs);
  // --- AB = h2 @ Wm1 ---
  k_gemm3<<<ceil_div(N,2),256,0,stream>>>(h, Wm1, AB, N);
  // --- edge MLP ---
  k_edge_mlp<<<ceil_div(E,256),256,0,stream>>>(csr_src, csr_dst, csr_eid, AB,
                                               bm1, Wm2, bm2, out, E);
}

// Round 12
// 409.158 us; speedup vs baseline: 1.2919x; 1.2919x over previous
//
#include <hip/hip_runtime.h>
#include <hip/hip_bf16.h>

// GCN (2-layer, PyG-style symmetric norm + self loops) + edge MLP.
//  - CSR by dst (hist -> 3-level scan -> fill). No fp32 atomics.
//  - gcn_conv: t' = (h@W)*dinv[row] (producer-side scale), then per-node:
//      out[v] = relu(dinv[v]*( t'[v] + sum_{(s,v)} t'[s] ) + b)
//  - Edge MLP: ef@Wm1 = A[src]+B[dst], A/B precomputed per node.
// R2: 3-level scan.  R3: edge_mlp in CSR order (107->63.6us).
// R4: per-node GEMMs fused into agg epilogue.  R5/R6: readlane batch + dinv
//     folded into producer rows (82->69.5us).  R7: REGRESSED (TLP starve).
// R8/R9: deeper scalar pipes plateaued (74.5us).  R10: slicing REGRESSED
//     (80.7us: bytes unchanged, overheads added).
// R11: float4 gather, 4 edges per dwordx4 load (grp=lane>>4 edge slot,
//     q=lane&15 feature quad), unsigned 32-bit offsets (SGPR base + voffset,
//     no 64-bit addr chains, no per-edge readlane, no LDS). Cuts per-edge
//     VALU ~20cy -> ~5cy and vmem instrs 4x; bytes unchanged.

#define HDIM 64
#define CDIM 16

static inline int ceil_div(int a, int b){ return (a+b-1)/b; }

__device__ inline float readlane_f(float v, int l){
  return __uint_as_float(__builtin_amdgcn_readlane(__float_as_uint(v), l));
}

__global__ void k_zero_i32(int* p, int n){
  int i = blockIdx.x*blockDim.x + threadIdx.x;
  if(i<n) p[i]=0;
}

__global__ void k_hist(const int* __restrict__ dst, int* __restrict__ cnt, int E){
  int e = blockIdx.x*blockDim.x + threadIdx.x;
  if(e<E) atomicAdd(&cnt[dst[e]], 1);
}

// Level 1: per-block (256 nodes) sum of cnt -> bsum[block]
__global__ __launch_bounds__(256) void k_blocksum(const int* __restrict__ cnt,
                                                  int* __restrict__ bsum, int N){
  __shared__ int part[4];
  int i = blockIdx.x*256 + threadIdx.x;
  int v = (i<N) ? cnt[i] : 0;
  #pragma unroll
  for(int off=32; off>0; off>>=1) v += __shfl_down(v, off, 64);
  if((threadIdx.x & 63)==0) part[threadIdx.x>>6] = v;
  __syncthreads();
  if(threadIdx.x==0) bsum[blockIdx.x] = part[0]+part[1]+part[2]+part[3];
}

// Level 2: one block scans the per-block sums (nb <= 1024) -> exclusive prefix.
__global__ __launch_bounds__(1024) void k_scan_bsums(int* __restrict__ bsum, int nb){
  __shared__ int tmp[1024];
  int tid = threadIdx.x;
  int v = (tid<nb) ? bsum[tid] : 0;
  tmp[tid] = v; __syncthreads();
  for(int off=1; off<1024; off<<=1){
    int add = (tid>=off) ? tmp[tid-off] : 0;
    __syncthreads();
    tmp[tid] += add;
    __syncthreads();
  }
  if(tid<nb) bsum[tid] = tmp[tid] - v;   // exclusive
}

// Level 3: in-block exclusive scan of cnt + block offset -> row_start/cursor.
// Also computes dinv (needs only cnt).
__global__ __launch_bounds__(256) void k_write_prefix(const int* __restrict__ cnt,
                                                      const int* __restrict__ bsum,
                                                      int* __restrict__ row_start,
                                                      int* __restrict__ cursor,
                                                      float* __restrict__ dinv, int N){
  __shared__ int tmp[256];
  int tid = threadIdx.x;
  int i = blockIdx.x*256 + tid;
  int v = (i<N) ? cnt[i] : 0;
  tmp[tid] = v; __syncthreads();
  for(int off=1; off<256; off<<=1){
    int add = (tid>=off) ? tmp[tid-off] : 0;
    __syncthreads();
    tmp[tid] += add;
    __syncthreads();
  }
  if(i<N){
    int ex = bsum[blockIdx.x] + tmp[tid] - v;
    row_start[i] = ex;
    cursor[i]    = ex;
    dinv[i]      = 1.0f / sqrtf(1.0f + (float)v);  // deg >= 1 via self-loop
  }
}

__global__ void k_fill(const int* __restrict__ src, const int* __restrict__ dst,
                       int* __restrict__ cursor,
                       int* __restrict__ csr_src, int* __restrict__ csr_dst,
                       int* __restrict__ csr_eid, int E){
  int e = blockIdx.x*blockDim.x + threadIdx.x;
  if(e>=E) return;
  int s = src[e], d = dst[e];
  int pos = atomicAdd(&cursor[d], 1);
  csr_src[pos] = s;
  csr_dst[pos] = d;
  csr_eid[pos] = e;
}

// out[n][c] = (sum_k in[n][k] * W[k][c]) * dscale[n]; one block = 4 nodes,
// input rows staged in LDS, W coalesced + L1-resident.
template<int K, int COLS>
__global__ __launch_bounds__(256) void k_gemm(const float* __restrict__ in,
                                              const float* __restrict__ W,
                                              const float* __restrict__ dscale,
                                              float* __restrict__ out, int N){
  const int NODES = 256/COLS;
  __shared__ float srow[NODES*K];
  int n0 = blockIdx.x*NODES;
  for(int i=threadIdx.x; i<NODES*K; i+=256){
    int g = n0*K + i;
    srow[i] = (g < N*K) ? in[g] : 0.f;
  }
  __syncthreads();
  int c = threadIdx.x % COLS;
  int y = threadIdx.x / COLS;
  int n = n0+y;
  if(n>=N) return;
  float acc=0.f;
  #pragma unroll
  for(int k=0;k<K;k++) acc += srow[y*K+k]*W[k*COLS+c];
  out[n*COLS+c]=acc*dscale[n];
}

// Fused: float4 gather-aggregate over pre-scaled t' -> r = relu(acc*dv + b)
// -> per-node GEMM epilogue vs Wepi via readlane broadcast (no LDS/barrier).
// Lane layout: grp = lane>>4 (edge slot 0..3), q = lane&15 (feature quad).
// Per 16 edges: 4 index loads (4-addr broadcast, L1-hit) + 4 dwordx4 gathers
// (1KB per instr) + 16 adds. Offsets all unsigned 32-bit (SGPR base+voffset).
template<int GROUPS, bool SCALE_OUT>
__global__ __launch_bounds__(256) void k_agg_fused(const float* __restrict__ t,
                                                   const int* __restrict__ csr_src,
                                                   const int* __restrict__ row_start,
                                                   const int* __restrict__ cnt,
                                                   const float* __restrict__ dinv,
                                                   const float* __restrict__ bias,
                                                   const float* __restrict__ Wepi,
                                                   float* __restrict__ outbuf, int N){
  int lane = threadIdx.x & 63;
  int w    = threadIdx.x >> 6;
  int v    = blockIdx.x*4 + w;
  bool act = (v < N);
  int vv   = act ? v : 0;
  int grp  = lane >> 4;
  int q    = lane & 15;
  const float4* __restrict__ t4 = (const float4*)t;

  float dv = dinv[vv];
  float4 selfq = t4[(unsigned)vv*16u + (unsigned)q];   // self term quad
  float4 acc0, acc1;
  acc0.x = (grp==0)? selfq.x : 0.f;
  acc0.y = (grp==0)? selfq.y : 0.f;
  acc0.z = (grp==0)? selfq.z : 0.f;
  acc0.w = (grp==0)? selfq.w : 0.f;
  acc1 = make_float4(0.f,0.f,0.f,0.f);

  int j0  = act ? row_start[vv] : 0;
  int deg = act ? cnt[vv] : 0;

  int k = 0;
  for(; k+16<=deg; k+=16){
    unsigned b = (unsigned)(j0 + k);
    int i0 = csr_src[b + grp];          // 4 distinct addrs, 1 line, L1-hit
    int i1 = csr_src[b + 4u + grp];
    int i2 = csr_src[b + 8u + grp];
    int i3 = csr_src[b + 12u + grp];
    float4 t0 = t4[(unsigned)i0*16u + q];   // 4 edges per dwordx4 instr
    float4 t1 = t4[(unsigned)i1*16u + q];
    float4 t2 = t4[(unsigned)i2*16u + q];
    float4 t3 = t4[(unsigned)i3*16u + q];
    acc0.x+=t0.x; acc0.y+=t0.y; acc0.z+=t0.z; acc0.w+=t0.w;
    acc1.x+=t1.x; acc1.y+=t1.y; acc1.z+=t1.z; acc1.w+=t1.w;
    acc0.x+=t2.x; acc0.y+=t2.y; acc0.z+=t2.z; acc0.w+=t2.w;
    acc1.x+=t3.x; acc1.y+=t3.y; acc1.z+=t3.z; acc1.w+=t3.w;
  }
  for(; k<deg; k+=4){                   // tail: 4 edges/iter, mask via fma
    int pos  = k + grp;
    int posc = pos<deg ? pos : deg-1;
    int ii = csr_src[(unsigned)(j0 + posc)];
    float4 tv = t4[(unsigned)ii*16u + q];
    float m = (pos<deg) ? 1.f : 0.f;
    acc0.x += tv.x*m; acc0.y += tv.y*m; acc0.z += tv.z*m; acc0.w += tv.w*m;
  }

  float4 a;
  a.x = acc0.x + acc1.x;
  a.y = acc0.y + acc1.y;
  a.z = acc0.z + acc1.z;
  a.w = acc0.w + acc1.w;
  a.x += __shfl_xor(a.x, 16, 64);  a.x += __shfl_xor(a.x, 32, 64);
  a.y += __shfl_xor(a.y, 16, 64);  a.y += __shfl_xor(a.y, 32, 64);
  a.z += __shfl_xor(a.z, 16, 64);  a.z += __shfl_xor(a.z, 32, 64);
  a.w += __shfl_xor(a.w, 16, 64);  a.w += __shfl_xor(a.w, 32, 64);

  float4 b4 = ((const float4*)bias)[q];
  float4 r;
  r.x = a.x*dv + b4.x;  r.x = r.x>0.f ? r.x : 0.f;
  r.y = a.y*dv + b4.y;  r.y = r.y>0.f ? r.y : 0.f;
  r.z = a.z*dv + b4.z;  r.z = r.z>0.f ? r.z : 0.f;
  r.w = a.w*dv + b4.w;  r.w = r.w>0.f ? r.w : 0.f;
  // lane (grp,q) holds h-row features [4q..4q+3] (groups duplicate)

  float s_out[GROUPS];
  #pragma unroll
  for(int g=0; g<GROUPS; g++) s_out[g] = 0.f;
  #pragma unroll
  for(int q2=0; q2<16; q2++){
    float h0 = readlane_f(r.x, q2);      // feature q2*4+0
    float h1 = readlane_f(r.y, q2);
    float h2 = readlane_f(r.z, q2);
    float h3 = readlane_f(r.w, q2);
    #pragma unroll
    for(int g=0; g<GROUPS; g++){
      s_out[g] += h0 * Wepi[(unsigned)((g*HDIM + q2*4+0)*HDIM + lane)];
      s_out[g] += h1 * Wepi[(unsigned)((g*HDIM + q2*4+1)*HDIM + lane)];
      s_out[g] += h2 * Wepi[(unsigned)((g*HDIM + q2*4+2)*HDIM + lane)];
      s_out[g] += h3 * Wepi[(unsigned)((g*HDIM + q2*4+3)*HDIM + lane)];
    }
  }
  if(act){
    #pragma unroll
    for(int g=0; g<GROUPS; g++){
      float o = SCALE_OUT ? s_out[g]*dv : s_out[g];
      outbuf[(size_t)v*(GROUPS*HDIM) + g*HDIM + lane] = o;
    }
  }
}

// Edge MLP in CSR(dst) order: thread j -> (s, d, eid). Consecutive threads share
// d -> B[d] reads broadcast/stream. A[s] random: 16 float4 loads in flight.
__global__ __launch_bounds__(256) void k_edge_mlp(const int* __restrict__ csr_src,
                                                  const int* __restrict__ csr_dst,
                                                  const int* __restrict__ csr_eid,
                                                  const float* __restrict__ AB,
                                                  const float* __restrict__ bm1,
                                                  const float* __restrict__ Wm2,
                                                  const float* __restrict__ bm2,
                                                  float* __restrict__ out, int E){
  int j = blockIdx.x*blockDim.x + threadIdx.x;
  if(j>=E) return;
  int s = csr_src[j], d = csr_dst[j], eid = csr_eid[j];
  const float4* Af = (const float4*)(AB + (size_t)s*128);
  const float4* Bf = (const float4*)(AB + (size_t)d*128 + 64);
  const float4* bm1f = (const float4*)bm1;
  const float4* bm2f = (const float4*)bm2;

  float4 a[16];
  #pragma unroll
  for(int k0=0;k0<16;k0++) a[k0] = Af[k0];   // random-side gather, 16 in flight

  float acc[CDIM];
  {
    float4 c0 = bm2f[0], c1 = bm2f[1], c2 = bm2f[2], c3 = bm2f[3];
    acc[0]=c0.x; acc[1]=c0.y; acc[2]=c0.z; acc[3]=c0.w;
    acc[4]=c1.x; acc[5]=c1.y; acc[6]=c1.z; acc[7]=c1.w;
    acc[8]=c2.x; acc[9]=c2.y; acc[10]=c2.z; acc[11]=c2.w;
    acc[12]=c3.x; acc[13]=c3.y; acc[14]=c3.z; acc[15]=c3.w;
  }
  #pragma unroll
  for(int k0=0;k0<16;k0++){
    float4 b  = Bf[k0];     // same d across wave -> broadcast / L1-hit
    float4 bb = bm1f[k0];   // wave-uniform -> s_load
    float z0 = a[k0].x+b.x+bb.x; z0 = z0>0.f? z0:0.f;
    float z1 = a[k0].y+b.y+bb.y; z1 = z1>0.f? z1:0.f;
    float z2 = a[k0].z+b.z+bb.z; z2 = z2>0.f? z2:0.f;
    float z3 = a[k0].w+b.w+bb.w; z3 = z3>0.f? z3:0.f;
    #pragma unroll
    for(int c=0;c<CDIM;c++){
      acc[c] += z0 * Wm2[(k0*4+0)*CDIM + c];
      acc[c] += z1 * Wm2[(k0*4+1)*CDIM + c];
      acc[c] += z2 * Wm2[(k0*4+2)*CDIM + c];
      acc[c] += z3 * Wm2[(k0*4+3)*CDIM + c];
    }
  }
  float4* o = (float4*)(out + (size_t)eid*CDIM);
  o[0] = make_float4(acc[0],acc[1],acc[2],acc[3]);
  o[1] = make_float4(acc[4],acc[5],acc[6],acc[7]);
  o[2] = make_float4(acc[8],acc[9],acc[10],acc[11]);
  o[3] = make_float4(acc[12],acc[13],acc[14],acc[15]);
}

extern "C" void kernel_launch(void* const* d_in, const int* in_sizes, int n_in,
                              void* d_out, int out_size, void* d_ws, size_t ws_size,
                              hipStream_t stream) {
  const float* x   = (const float*)d_in[0];
  const int*   ei  = (const int*)  d_in[1];
  const float* W1  = (const float*)d_in[2];
  const float* b1  = (const float*)d_in[3];
  const float* W2  = (const float*)d_in[4];
  const float* b2  = (const float*)d_in[5];
  const float* Wm1 = (const float*)d_in[6];
  const float* bm1 = (const float*)d_in[7];
  const float* Wm2 = (const float*)d_in[8];
  const float* bm2 = (const float*)d_in[9];
  float* out = (float*)d_out;

  const int N = in_sizes[0]/128;
  const int E = in_sizes[1]/2;
  const int* src = ei;
  const int* dst = ei + E;

  const int NB = ceil_div(N,256);

  // ws layout (256B-aligned). t1 (N*64) aliases AB's low half: t1 is dead
  // (last read by aggF<1>) before aggF<2> writes AB.
  char* ws = (char*)d_ws;
  size_t off = 0;
  auto alloc = [&](size_t bytes)->char*{
    char* p = ws + off; off += (bytes + 255) & ~(size_t)255; return p;
  };
  int*   cnt       = (int*)  alloc((size_t)N*4);
  int*   row_start = (int*)  alloc((size_t)N*4);
  int*   cursor    = (int*)  alloc((size_t)N*4);
  float* dinv      = (float*)alloc((size_t)N*4);
  int*   bsum      = (int*)  alloc((size_t)NB*4);
  int*   csr_src   = (int*)  alloc((size_t)E*4);
  int*   csr_dst   = (int*)  alloc((size_t)E*4);
  int*   csr_eid   = (int*)  alloc((size_t)E*4);
  float* AB        = (float*)alloc((size_t)N*128*4);
  float* t1        = AB;                               // alias: low 12.8MB of AB
  float* t2        = (float*)alloc((size_t)N*64*4);

  // --- CSR build ---
  k_zero_i32    <<<ceil_div(N,256),256,0,stream>>>(cnt, N);
  k_hist        <<<ceil_div(E,256),256,0,stream>>>(dst, cnt, E);
  k_blocksum    <<<NB,256,0,stream>>>(cnt, bsum, N);
  k_scan_bsums  <<<1,1024,0,stream>>>(bsum, NB);
  k_write_prefix<<<NB,256,0,stream>>>(cnt, bsum, row_start, cursor, dinv, N);
  k_fill        <<<ceil_div(E,256),256,0,stream>>>(src, dst, cursor,
                                                   csr_src, csr_dst, csr_eid, E);

  // --- layer 1: t1' = (x@W1)*dinv ---
  k_gemm<128,64><<<ceil_div(N,4),256,0,stream>>>(x, W1, dinv, t1, N);
  // --- agg1 + fused (h1@W2), output pre-scaled: t2' ---
  k_agg_fused<1,true ><<<ceil_div(N,4),256,0,stream>>>(t1, csr_src, row_start, cnt,
                                                       dinv, b1, W2, t2, N);
  // --- agg2 + fused (h2@Wm1): AB (unscaled) ---
  k_agg_fused<2,false><<<ceil_div(N,4),256,0,stream>>>(t2, csr_src, row_start, cnt,
                                                       dinv, b2, Wm1, AB, N);
  // --- edge MLP ---
  k_edge_mlp<<<ceil_div(E,256),256,0,stream>>>(csr_src, csr_dst, csr_eid, AB,
                                               bm1, Wm2, bm2, out, E);
}